// Round 1
// baseline (561.257 us; speedup 1.0000x reference)
//
#include <hip/hip_runtime.h>

#define N_NODES 200000
#define N_EDGES 3200000
#define FEATS   256
#define NC      32

// hardware f32 atomic add (avoid CAS-loop lowering without -munsafe-fp-atomics)
__device__ __forceinline__ float atomAddF(float* p, float v) {
    return unsafeAtomicAdd(p, v);
}

// ---------------------------------------------------------------------------
// Kernel 1: h = x @ W^T + bias   [N,32]
// Fused epilogue: S1[c] += (u[n]/N)*h[n,c],  S2 += ((u[n]/N)*h[n,c])^2
// Block = 256 threads, processes 16 rows per iteration.
// LDS: W as [k][c] (32 KB, lanes differ in c -> conflict-free),
//      x tile [16][256] (16 KB, reads are 2-address broadcasts -> free).
// ---------------------------------------------------------------------------
__global__ __launch_bounds__(256) void k_linear(
    const float* __restrict__ x, const float* __restrict__ Wmat,
    const float* __restrict__ bias, const float* __restrict__ u_sum,
    float* __restrict__ h, float* __restrict__ S1, float* __restrict__ S2)
{
    __shared__ float wl[FEATS * NC];   // [k][c]  32 KB
    __shared__ float xl[16 * FEATS];   // [r][k]  16 KB
    __shared__ float red[256];

    for (int i = threadIdx.x; i < NC * FEATS; i += 256) {
        int c = i >> 8, k = i & 255;
        wl[k * NC + c] = Wmat[i];
    }

    const int c  = threadIdx.x & 31;
    const int rq = threadIdx.x >> 5;        // 0..7 -> rows rq*2, rq*2+1
    const float b = bias[c];
    const float invn = 1.0f / (float)N_NODES;
    float s1 = 0.f, s2 = 0.f;

    for (int base = blockIdx.x * 16; base < N_NODES; base += gridDim.x * 16) {
        __syncthreads();                    // also covers initial W load
        for (int i = threadIdx.x; i < 16 * FEATS; i += 256)
            xl[i] = x[(size_t)base * FEATS + i];
        __syncthreads();

        const float* xr0 = &xl[(rq * 2 + 0) * FEATS];
        const float* xr1 = &xl[(rq * 2 + 1) * FEATS];
        float acc0 = b, acc1 = b;
        #pragma unroll 8
        for (int k = 0; k < FEATS; k += 4) {
            float4 x0 = *(const float4*)(xr0 + k);
            float4 x1 = *(const float4*)(xr1 + k);
            float w0 = wl[(k + 0) * NC + c];
            float w1 = wl[(k + 1) * NC + c];
            float w2 = wl[(k + 2) * NC + c];
            float w3 = wl[(k + 3) * NC + c];
            acc0 = fmaf(x0.x, w0, acc0); acc1 = fmaf(x1.x, w0, acc1);
            acc0 = fmaf(x0.y, w1, acc0); acc1 = fmaf(x1.y, w1, acc1);
            acc0 = fmaf(x0.z, w2, acc0); acc1 = fmaf(x1.z, w2, acc1);
            acc0 = fmaf(x0.w, w3, acc0); acc1 = fmaf(x1.w, w3, acc1);
        }

        const int r0 = base + rq * 2, r1 = r0 + 1;
        h[(size_t)r0 * NC + c] = acc0;
        h[(size_t)r1 * NC + c] = acc1;
        float a0 = u_sum[r0] * invn * acc0;
        float a1 = u_sum[r1] * invn * acc1;
        s1 += a0 + a1;
        s2 += a0 * a0 + a1 * a1;
    }

    // block-level reduction of S1 (per class) and S2 (scalar)
    __syncthreads();
    red[threadIdx.x] = s1;
    __syncthreads();
    if (threadIdx.x < 32) {
        float t = 0.f;
        #pragma unroll
        for (int j = 0; j < 8; ++j) t += red[threadIdx.x + 32 * j];
        atomAddF(&S1[threadIdx.x], t);
    }
    __syncthreads();
    red[threadIdx.x] = s2;
    __syncthreads();
    for (int off = 128; off > 0; off >>= 1) {
        if (threadIdx.x < off) red[threadIdx.x] += red[threadIdx.x + off];
        __syncthreads();
    }
    if (threadIdx.x == 0) atomAddF(S2, red[0]);
}

// ---------------------------------------------------------------------------
// Kernel 2: y[dst[e]][c] += h[src[e]][c] * w[e]   (32 lanes per edge)
// ---------------------------------------------------------------------------
__global__ __launch_bounds__(256) void k_scatter(
    const float* __restrict__ h, const float* __restrict__ w,
    const int* __restrict__ src, const int* __restrict__ dst,
    float* __restrict__ y)
{
    const long long total  = (long long)N_EDGES * NC;
    const long long stride = (long long)gridDim.x * 256;
    for (long long i = (long long)blockIdx.x * 256 + threadIdx.x;
         i < total; i += stride) {
        const int e = (int)(i >> 5);
        const int c = (int)(i & 31);
        const float v = h[(size_t)src[e] * NC + c] * w[e];
        atomAddF(&y[(size_t)dst[e] * NC + c], v);
    }
}

// ---------------------------------------------------------------------------
// Kernel 3: colsum[c] = sum_n y[n][c]
// ---------------------------------------------------------------------------
__global__ __launch_bounds__(256) void k_colsum(
    const float* __restrict__ y, float* __restrict__ colsum)
{
    __shared__ float red[256];
    const long long total  = (long long)N_NODES * NC;
    const long long stride = (long long)gridDim.x * 256;
    float s = 0.f;
    for (long long i = (long long)blockIdx.x * 256 + threadIdx.x;
         i < total; i += stride)
        s += y[i];                       // c = i & 31 is constant per thread
    red[threadIdx.x] = s;
    __syncthreads();
    if (threadIdx.x < 32) {
        float t = 0.f;
        #pragma unroll
        for (int j = 0; j < 8; ++j) t += red[threadIdx.x + 32 * j];
        atomAddF(&colsum[threadIdx.x], t);
    }
}

// ---------------------------------------------------------------------------
// Kernel 4: loss = (S2 - 2*sum_c m_c*S1_c + N*sum_c m_c^2) / (N*C)
// acc layout: [0..31] colsum_y, [32..63] S1, [64] S2
// ---------------------------------------------------------------------------
__global__ void k_final(const float* __restrict__ acc, float* __restrict__ loss_out)
{
    double cross = 0.0, msq = 0.0;
    for (int c = 0; c < NC; ++c) {
        double m = (double)acc[c] / (double)N_NODES;
        cross += m * (double)acc[32 + c];
        msq   += m * m;
    }
    double loss = ((double)acc[64] - 2.0 * cross + (double)N_NODES * msq)
                  / ((double)N_NODES * (double)NC);
    *loss_out = (float)loss;
}

extern "C" void kernel_launch(void* const* d_in, const int* in_sizes, int n_in,
                              void* d_out, int out_size, void* d_ws, size_t ws_size,
                              hipStream_t stream)
{
    const float* x   = (const float*)d_in[0];
    const float* w   = (const float*)d_in[1];
    const float* u   = (const float*)d_in[2];
    const float* Wm  = (const float*)d_in[3];
    const float* Wb  = (const float*)d_in[4];
    const int*   src = (const int*)d_in[5];
    const int*   dst = (const int*)d_in[6];

    float* out = (float*)d_out;                 // y [N*32] then loss [1]
    float* acc = (float*)d_ws;                  // 65 floats used
    float* h   = (float*)d_ws + 256;            // [N,32]

    // harness poisons d_out/d_ws with 0xAA and does not re-poison between replays
    hipMemsetAsync(d_out, 0, (size_t)out_size * sizeof(float), stream);
    hipMemsetAsync(d_ws, 0, 256 * sizeof(float), stream);

    k_linear <<<2048, 256, 0, stream>>>(x, Wm, Wb, u, h, acc + 32, acc + 64);
    k_scatter<<<8192, 256, 0, stream>>>(h, w, src, dst, out);
    k_colsum <<<2048, 256, 0, stream>>>(out, acc);
    k_final  <<<1, 1, 0, stream>>>(acc, out + (size_t)N_NODES * NC);
}